// Round 4
// baseline (333.311 us; speedup 1.0000x reference)
//
#include <hip/hip_runtime.h>
#include <math.h>

typedef __attribute__((ext_vector_type(4))) float f32x4;
typedef __attribute__((ext_vector_type(8))) short short8;

#define NEG_INF (-__builtin_inff())

__device__ __forceinline__ unsigned short f2bf(float f) {
    union { float f; unsigned u; } v; v.f = f;
    unsigned r = v.u + 0x7FFFu + ((v.u >> 16) & 1u);
    return (unsigned short)(r >> 16);
}
__device__ __forceinline__ float bf2f(unsigned short h) {
    union { unsigned u; float f; } v; v.u = ((unsigned)h) << 16;
    return v.f;
}

__device__ __forceinline__ f32x4 mfma_bf16(short8 a, short8 b, f32x4 c) {
    return __builtin_amdgcn_mfma_f32_16x16x32_bf16(a, b, c, 0, 0, 0);
}

// ---------------------------------------------------------------------------
// Split fp32 -> (bf16 hi, bf16 lo) arrays, 4 elements per thread
// ---------------------------------------------------------------------------
__global__ void split_kernel(const float* __restrict__ in,
                             unsigned short* __restrict__ hi,
                             unsigned short* __restrict__ lo, int n4)
{
    int i = blockIdx.x * 256 + threadIdx.x;
    if (i >= n4) return;
    float4 v = ((const float4*)in)[i];
    ushort4 h, l;
    h.x = f2bf(v.x); l.x = f2bf(v.x - bf2f(h.x));
    h.y = f2bf(v.y); l.y = f2bf(v.y - bf2f(h.y));
    h.z = f2bf(v.z); l.z = f2bf(v.z - bf2f(h.z));
    h.w = f2bf(v.w); l.w = f2bf(v.w - bf2f(h.w));
    ((ushort4*)hi)[i] = h;
    ((ushort4*)lo)[i] = l;
}

// ---------------------------------------------------------------------------
// Projection GEMM (unchanged this round): qkvgr = x @ W^T
// ---------------------------------------------------------------------------
__global__ __launch_bounds__(256, 2)
void gemm_proj(const unsigned short* __restrict__ xh, const unsigned short* __restrict__ xl,
               const unsigned short* __restrict__ wh, const unsigned short* __restrict__ wl,
               unsigned short* __restrict__ Qh, unsigned short* __restrict__ Ql,
               unsigned short* __restrict__ Kh, unsigned short* __restrict__ Kl,
               unsigned short* __restrict__ Vtg, float* __restrict__ gbuf)
{
    __shared__ __align__(16) unsigned short As[2][128][40];
    __shared__ __align__(16) unsigned short Bs[2][128][40];
    const int mt = blockIdx.x & 31;
    const int nt = blockIdx.x >> 5;
    const int m0 = mt * 128, n0 = nt * 128;
    const int tid = threadIdx.x;
    const int w = tid >> 6, l = tid & 63;
    const int wm = w >> 1, wn = w & 1;
    const int lr = l & 15, lq = l >> 4;
    const bool needLo = (nt < 16) || (nt == 24);

    f32x4 acc[4][4];
#pragma unroll
    for (int i = 0; i < 4; ++i)
#pragma unroll
        for (int j = 0; j < 4; ++j) acc[i][j] = (f32x4){0.f, 0.f, 0.f, 0.f};

    const int srow = tid >> 2;
    const int scol = (tid & 3) * 8;

    for (int k0 = 0; k0 < 1024; k0 += 32) {
        __syncthreads();
#pragma unroll
        for (int p = 0; p < 2; ++p) {
            int r = srow + p * 64;
            *(uint4*)&As[0][r][scol] =
                *(const uint4*)&xh[(size_t)(m0 + r) * 1024 + k0 + scol];
            if (needLo)
                *(uint4*)&As[1][r][scol] =
                    *(const uint4*)&xl[(size_t)(m0 + r) * 1024 + k0 + scol];
            int o = n0 + r;
            uint4 b4 = make_uint4(0, 0, 0, 0), b4l = make_uint4(0, 0, 0, 0);
            if (o < 3088) {
                b4 = *(const uint4*)&wh[(size_t)o * 1024 + k0 + scol];
                if (needLo) b4l = *(const uint4*)&wl[(size_t)o * 1024 + k0 + scol];
            }
            *(uint4*)&Bs[0][r][scol] = b4;
            if (needLo) *(uint4*)&Bs[1][r][scol] = b4l;
        }
        __syncthreads();

        short8 ah[4], al[4], bh[4], bl[4];
#pragma unroll
        for (int i = 0; i < 4; ++i) {
            ah[i] = *(const short8*)&As[0][wm * 64 + i * 16 + lr][lq * 8];
            bh[i] = *(const short8*)&Bs[0][wn * 64 + i * 16 + lr][lq * 8];
        }
        if (needLo) {
#pragma unroll
            for (int i = 0; i < 4; ++i) {
                al[i] = *(const short8*)&As[1][wm * 64 + i * 16 + lr][lq * 8];
                bl[i] = *(const short8*)&Bs[1][wn * 64 + i * 16 + lr][lq * 8];
            }
        }
#pragma unroll
        for (int i = 0; i < 4; ++i)
#pragma unroll
            for (int j = 0; j < 4; ++j) {
                acc[i][j] = mfma_bf16(ah[i], bh[j], acc[i][j]);
                if (needLo) {
                    acc[i][j] = mfma_bf16(ah[i], bl[j], acc[i][j]);
                    acc[i][j] = mfma_bf16(al[i], bh[j], acc[i][j]);
                }
            }
    }

#pragma unroll
    for (int i = 0; i < 4; ++i) {
        int nrow0 = m0 + wm * 64 + i * 16 + lq * 4;
        int b = nrow0 >> 11;
        int tbase = nrow0 & 2047;
#pragma unroll
        for (int j = 0; j < 4; ++j) {
            int o = n0 + wn * 64 + j * 16 + lr;
            if (o < 1024) {
                int h = o >> 6, d = o & 63;
                size_t base = ((size_t)(b * 16 + h) * 2048 + tbase) * 64 + d;
#pragma unroll
                for (int r = 0; r < 4; ++r) {
                    float v = acc[i][j][r];
                    unsigned short hi_ = f2bf(v);
                    unsigned short lo_ = f2bf(v - bf2f(hi_));
                    Qh[base + (size_t)r * 64] = hi_;
                    Ql[base + (size_t)r * 64] = lo_;
                }
            } else if (o < 2048) {
                int oo = o - 1024;
                int h = oo >> 6, d = oo & 63;
                size_t base = ((size_t)(b * 16 + h) * 2048 + tbase) * 64 + d;
#pragma unroll
                for (int r = 0; r < 4; ++r) {
                    float v = acc[i][j][r];
                    unsigned short hi_ = f2bf(v);
                    unsigned short lo_ = f2bf(v - bf2f(hi_));
                    Kh[base + (size_t)r * 64] = hi_;
                    Kl[base + (size_t)r * 64] = lo_;
                }
            } else if (o < 3072) {
                int oo = o - 2048;
                int h = oo >> 6, d = oo & 63;
                size_t base = ((size_t)(b * 16 + h) * 64 + d) * 2048 + tbase;
                ushort4 pk;
                pk.x = f2bf(acc[i][j][0]);
                pk.y = f2bf(acc[i][j][1]);
                pk.z = f2bf(acc[i][j][2]);
                pk.w = f2bf(acc[i][j][3]);
                *(ushort4*)&Vtg[base] = pk;
            } else if (o < 3088) {
                int og = o - 3072;
#pragma unroll
                for (int r = 0; r < 4; ++r)
                    gbuf[(size_t)(nrow0 + r) * 16 + og] = acc[i][j][r];
            }
        }
    }
}

// ---------------------------------------------------------------------------
// Gate scan (unchanged): logG2[bh][t] = cumsum log_sigmoid * log2(e)
// ---------------------------------------------------------------------------
__global__ void gate_scan(const float* __restrict__ g, float* __restrict__ lg)
{
    const int bh = blockIdx.x;
    const int b = bh >> 4, h = bh & 15;
    const int tid = threadIdx.x;
    __shared__ float part[256];

    float vals[8];
    float run = 0.f;
#pragma unroll
    for (int j = 0; j < 8; ++j) {
        int t = tid * 8 + j;
        float x = g[(size_t)(b * 2048 + t) * 16 + h];
        float ls = fminf(x, 0.f) - log1pf(__expf(-fabsf(x)));
        run += ls * 1.4426950408889634f;
        vals[j] = run;
    }
    part[tid] = run;
    __syncthreads();
    for (int ofs = 1; ofs < 256; ofs <<= 1) {
        float add = (tid >= ofs) ? part[tid - ofs] : 0.f;
        __syncthreads();
        part[tid] += add;
        __syncthreads();
    }
    float excl = part[tid] - run;
#pragma unroll
    for (int j = 0; j < 8; ++j)
        lg[(size_t)bh * 2048 + tid * 8 + j] = excl + vals[j];
}

// ---------------------------------------------------------------------------
// Flash-style causal gated power attention — pipelined + balanced + linear-SM.
//  * qi remap: each CU's resident blocks get qi {a,a+8,a+16,a+24} (balance)
//  * T14 reg-staging: next tile's global loads issue at compute start
//  * linear-domain online softmax: w = (|S|+eps)^2 * 2^(gq-gs); no log2
//  * rcp guarded: Mn > 1e-30 (denormal Mn -> v_rcp = inf -> 0*inf = NaN)
//  * XOR-swizzled LDS (chunk ^= row&7), no pads: 32KB -> 4 blocks/CU
// ---------------------------------------------------------------------------
__global__ __launch_bounds__(256, 4)
void attn_fwd(const unsigned short* __restrict__ Qh, const unsigned short* __restrict__ Ql,
              const unsigned short* __restrict__ Kh, const unsigned short* __restrict__ Kl,
              const unsigned short* __restrict__ Vtg, const float* __restrict__ lg,
              float* __restrict__ out)
{
    __shared__ __align__(16) unsigned short kh[64][64];
    __shared__ __align__(16) unsigned short kl[64][64];
    __shared__ __align__(16) unsigned short vs[64][64];   // [d][s]
    __shared__ __align__(16) unsigned short pl[4][16][64];

    const int bid = blockIdx.x;
    const int qi = (bid & 7) | ((bid >> 8) << 3);   // balance remap
    const int bh = (bid >> 3) & 31;
    const int tid = threadIdx.x;
    const int w = tid >> 6, l = tid & 63;
    const int lr = l & 15, lq = l >> 4;
    const int xk = lr & 7;
    const int q0 = qi * 64;
    const int myrow0 = q0 + w * 16;

    const size_t qoff = ((size_t)bh * 2048 + myrow0 + lr) * 64;
    short8 qh8[2], ql8[2];
    qh8[0] = *(const short8*)&Qh[qoff + lq * 8];
    qh8[1] = *(const short8*)&Qh[qoff + 32 + lq * 8];
    ql8[0] = *(const short8*)&Ql[qoff + lq * 8];
    ql8[1] = *(const short8*)&Ql[qoff + 32 + lq * 8];

    float gq2[4];
#pragma unroll
    for (int r = 0; r < 4; ++r)
        gq2[r] = lg[(size_t)bh * 2048 + myrow0 + lq * 4 + r] - 3.0f;  // + log2(1/8)

    float M_[4]  = {0.f, 0.f, 0.f, 0.f};
    float ls_[4] = {0.f, 0.f, 0.f, 0.f};
    f32x4 o4[4];
#pragma unroll
    for (int i = 0; i < 4; ++i) o4[i] = (f32x4){0.f, 0.f, 0.f, 0.f};

    // staging geometry: 256 thr x 16B covers 32 rows/pass, 2 passes per buffer
    const int srow = tid >> 3;          // 0..31
    const int schunk = tid & 7;         // 16B chunk
    const int swc = ((schunk ^ (srow & 7)) << 3);  // swizzled col (shorts)

    uint4 krh[2], krl[2], vr[2];
    float gsp[4];

    auto LOADT = [&](int kv0) {
        size_t kb = ((size_t)bh * 2048 + kv0 + srow) * 64 + schunk * 8;
        krh[0] = *(const uint4*)&Kh[kb];
        krh[1] = *(const uint4*)&Kh[kb + 32 * 64];
        krl[0] = *(const uint4*)&Kl[kb];
        krl[1] = *(const uint4*)&Kl[kb + 32 * 64];
        size_t vb = ((size_t)bh * 64 + srow) * 2048 + kv0 + schunk * 8;
        vr[0] = *(const uint4*)&Vtg[vb];
        vr[1] = *(const uint4*)&Vtg[vb + 32 * 2048];
#pragma unroll
        for (int js = 0; js < 4; ++js)
            gsp[js] = lg[(size_t)bh * 2048 + kv0 + js * 16 + lr];
    };

    LOADT(0);

    for (int kv0 = 0; kv0 <= q0; kv0 += 64) {
        __syncthreads();   // all waves done reading LDS of previous tile
        *(uint4*)&kh[srow][swc]      = krh[0];
        *(uint4*)&kh[srow + 32][swc] = krh[1];
        *(uint4*)&kl[srow][swc]      = krl[0];
        *(uint4*)&kl[srow + 32][swc] = krl[1];
        *(uint4*)&vs[srow][swc]      = vr[0];
        *(uint4*)&vs[srow + 32][swc] = vr[1];
        __syncthreads();   // LDS writes visible

        float gsl[4];
#pragma unroll
        for (int js = 0; js < 4; ++js) gsl[js] = gsp[js];

        if (kv0 + 64 <= q0) LOADT(kv0 + 64);   // overlap with compute below

        // ---- S = Q K^T (split-bf16, 3 MFMA) ----
        f32x4 sa[4];
#pragma unroll
        for (int js = 0; js < 4; ++js) sa[js] = (f32x4){0.f, 0.f, 0.f, 0.f};
#pragma unroll
        for (int js = 0; js < 4; ++js)
#pragma unroll
            for (int ks = 0; ks < 2; ++ks) {
                short8 kb  = *(const short8*)&kh[js * 16 + lr][((ks * 4 + lq) ^ xk) << 3];
                short8 kbl = *(const short8*)&kl[js * 16 + lr][((ks * 4 + lq) ^ xk) << 3];
                sa[js] = mfma_bf16(qh8[ks], kb,  sa[js]);
                sa[js] = mfma_bf16(qh8[ks], kbl, sa[js]);
                sa[js] = mfma_bf16(ql8[ks], kb,  sa[js]);
            }

        // ---- linear-domain scores: w = (|S|+eps)^2 * 2^(gq-gs) ----
        const bool diag = (kv0 == q0);
#pragma unroll
        for (int js = 0; js < 4; ++js) {
            float ga = gsl[js];
#pragma unroll
            for (int r = 0; r < 4; ++r) {
                float a = fabsf(sa[js][r]) + 1e-7f;
                float ex = exp2f(gq2[r] - ga);
                float wv = a * a * ex;
                if (diag && (js * 16 + lr > w * 16 + lq * 4 + r)) wv = 0.f;
                sa[js][r] = wv;
            }
        }

        // ---- online max/rescale (linear) ----
        float f_[4], rMv[4];
#pragma unroll
        for (int r = 0; r < 4; ++r) {
            float a = fmaxf(fmaxf(sa[0][r], sa[1][r]), fmaxf(sa[2][r], sa[3][r]));
#pragma unroll
            for (int msk = 1; msk < 16; msk <<= 1)
                a = fmaxf(a, __shfl_xor(a, msk, 16));
            float Mn = fmaxf(M_[r], a);
            // guard: Mn in denormal range -> v_rcp_f32 flushes input -> inf -> 0*inf = NaN.
            // any tile with max < 1e-30 is negligible vs the diagonal's >= 1.25e-15 floor.
            bool pos = Mn > 1e-30f;
            float rM = pos ? __builtin_amdgcn_rcpf(Mn) : 0.f;
            f_[r]  = pos ? M_[r] * rM : 1.f;
            rMv[r] = rM;
            M_[r]  = Mn;
        }

        float rs_[4] = {0.f, 0.f, 0.f, 0.f};
#pragma unroll
        for (int js = 0; js < 4; ++js)
#pragma unroll
            for (int r = 0; r < 4; ++r) {
                float pv = sa[js][r] * rMv[r];
                sa[js][r] = pv;
                rs_[r] += pv;
            }
#pragma unroll
        for (int r = 0; r < 4; ++r) {
            float s = rs_[r];
#pragma unroll
            for (int msk = 1; msk < 16; msk <<= 1)
                s += __shfl_xor(s, msk, 16);
            ls_[r] = ls_[r] * f_[r] + s;
        }
#pragma unroll
        for (int ds_ = 0; ds_ < 4; ++ds_)
#pragma unroll
            for (int r = 0; r < 4; ++r)
                o4[ds_][r] *= f_[r];

        // ---- P -> LDS (swizzled transpose, wave-local) ----
#pragma unroll
        for (int js = 0; js < 4; ++js)
#pragma unroll
            for (int r = 0; r < 4; ++r) {
                int prow = lq * 4 + r;
                int cch = (js * 2 + (lr >> 3)) ^ (prow & 7);
                pl[w][prow][(cch << 3) | (lr & 7)] = f2bf(sa[js][r]);
            }
        __asm__ volatile("s_waitcnt lgkmcnt(0)" ::: "memory");
        __builtin_amdgcn_sched_barrier(0);

        short8 pa0 = *(const short8*)&pl[w][lr][((0 + lq) ^ xk) << 3];
        short8 pa1 = *(const short8*)&pl[w][lr][((4 + lq) ^ xk) << 3];
#pragma unroll
        for (int ds_ = 0; ds_ < 4; ++ds_) {
            short8 vb0 = *(const short8*)&vs[ds_ * 16 + lr][((0 + lq) ^ xk) << 3];
            short8 vb1 = *(const short8*)&vs[ds_ * 16 + lr][((4 + lq) ^ xk) << 3];
            o4[ds_] = mfma_bf16(pa0, vb0, o4[ds_]);
            o4[ds_] = mfma_bf16(pa1, vb1, o4[ds_]);
        }
    }

    const int b = bh >> 4, h = bh & 15;
#pragma unroll
    for (int ds_ = 0; ds_ < 4; ++ds_)
#pragma unroll
        for (int r = 0; r < 4; ++r) {
            int t = myrow0 + lq * 4 + r;
            out[(size_t)(b * 2048 + t) * 1024 + h * 64 + ds_ * 16 + lr] =
                o4[ds_][r] / ls_[r];
        }
}

// ---------------------------------------------------------------------------
extern "C" void kernel_launch(void* const* d_in, const int* in_sizes, int n_in,
                              void* d_out, int out_size, void* d_ws, size_t ws_size,
                              hipStream_t stream)
{
    const float* x = (const float*)d_in[0];   // [2][2048][1024]
    const float* W = (const float*)d_in[1];   // [3088][1024]
    float* out = (float*)d_out;               // [2][2048][1024]

    const size_t NX = 4194304;    // 2*2048*1024
    const size_t NW = 3162112;    // 3088*1024
    const size_t NQ = 4194304;    // 32*2048*64

    char* ws = (char*)d_ws;
    size_t off = 0;
    auto alloc = [&](size_t bytes) -> void* {
        void* p = ws + off;
        off += (bytes + 255) & ~(size_t)255;
        return p;
    };
    unsigned short* xh = (unsigned short*)alloc(NX * 2);
    unsigned short* xl = (unsigned short*)alloc(NX * 2);
    unsigned short* wh = (unsigned short*)alloc(NW * 2);
    unsigned short* wl = (unsigned short*)alloc(NW * 2);
    unsigned short* Qh = (unsigned short*)alloc(NQ * 2);
    unsigned short* Ql = (unsigned short*)alloc(NQ * 2);
    unsigned short* Kh = (unsigned short*)alloc(NQ * 2);
    unsigned short* Kl = (unsigned short*)alloc(NQ * 2);
    unsigned short* Vt = (unsigned short*)alloc(NQ * 2);
    float* g  = (float*)alloc(65536 * 4);
    float* lg = (float*)alloc(65536 * 4);
    if (off > ws_size) return;

    split_kernel<<<(int)(NX / 4 + 255) / 256, 256, 0, stream>>>(x, xh, xl, (int)(NX / 4));
    split_kernel<<<(int)(NW / 4 + 255) / 256, 256, 0, stream>>>(W, wh, wl, (int)(NW / 4));
    gemm_proj<<<800, 256, 0, stream>>>(xh, xl, wh, wl, Qh, Ql, Kh, Kl, Vt, g);
    gate_scan<<<32, 256, 0, stream>>>(g, lg);
    attn_fwd<<<1024, 256, 0, stream>>>(Qh, Ql, Kh, Kl, Vt, lg, out);
}

// Round 6
// 324.705 us; speedup vs baseline: 1.0265x; 1.0265x over previous
//
#include <hip/hip_runtime.h>
#include <math.h>

typedef __attribute__((ext_vector_type(4))) float f32x4;
typedef __attribute__((ext_vector_type(8))) short short8;

#define NEG_INF (-__builtin_inff())

__device__ __forceinline__ unsigned short f2bf(float f) {
    union { float f; unsigned u; } v; v.f = f;
    unsigned r = v.u + 0x7FFFu + ((v.u >> 16) & 1u);
    return (unsigned short)(r >> 16);
}
__device__ __forceinline__ float bf2f(unsigned short h) {
    union { unsigned u; float f; } v; v.u = ((unsigned)h) << 16;
    return v.f;
}

__device__ __forceinline__ f32x4 mfma_bf16(short8 a, short8 b, f32x4 c) {
    return __builtin_amdgcn_mfma_f32_16x16x32_bf16(a, b, c, 0, 0, 0);
}

// ---------------------------------------------------------------------------
// Split fp32 -> (bf16 hi, bf16 lo) arrays, 4 elements per thread
// ---------------------------------------------------------------------------
__global__ void split_kernel(const float* __restrict__ in,
                             unsigned short* __restrict__ hi,
                             unsigned short* __restrict__ lo, int n4)
{
    int i = blockIdx.x * 256 + threadIdx.x;
    if (i >= n4) return;
    float4 v = ((const float4*)in)[i];
    ushort4 h, l;
    h.x = f2bf(v.x); l.x = f2bf(v.x - bf2f(h.x));
    h.y = f2bf(v.y); l.y = f2bf(v.y - bf2f(h.y));
    h.z = f2bf(v.z); l.z = f2bf(v.z - bf2f(h.z));
    h.w = f2bf(v.w); l.w = f2bf(v.w - bf2f(h.w));
    ((ushort4*)hi)[i] = h;
    ((ushort4*)lo)[i] = l;
}

// ---------------------------------------------------------------------------
// Projection GEMM (unchanged this round): qkvgr = x @ W^T
// ---------------------------------------------------------------------------
__global__ __launch_bounds__(256, 2)
void gemm_proj(const unsigned short* __restrict__ xh, const unsigned short* __restrict__ xl,
               const unsigned short* __restrict__ wh, const unsigned short* __restrict__ wl,
               unsigned short* __restrict__ Qh, unsigned short* __restrict__ Ql,
               unsigned short* __restrict__ Kh, unsigned short* __restrict__ Kl,
               unsigned short* __restrict__ Vtg, float* __restrict__ gbuf)
{
    __shared__ __align__(16) unsigned short As[2][128][40];
    __shared__ __align__(16) unsigned short Bs[2][128][40];
    const int mt = blockIdx.x & 31;
    const int nt = blockIdx.x >> 5;
    const int m0 = mt * 128, n0 = nt * 128;
    const int tid = threadIdx.x;
    const int w = tid >> 6, l = tid & 63;
    const int wm = w >> 1, wn = w & 1;
    const int lr = l & 15, lq = l >> 4;
    const bool needLo = (nt < 16) || (nt == 24);

    f32x4 acc[4][4];
#pragma unroll
    for (int i = 0; i < 4; ++i)
#pragma unroll
        for (int j = 0; j < 4; ++j) acc[i][j] = (f32x4){0.f, 0.f, 0.f, 0.f};

    const int srow = tid >> 2;
    const int scol = (tid & 3) * 8;

    for (int k0 = 0; k0 < 1024; k0 += 32) {
        __syncthreads();
#pragma unroll
        for (int p = 0; p < 2; ++p) {
            int r = srow + p * 64;
            *(uint4*)&As[0][r][scol] =
                *(const uint4*)&xh[(size_t)(m0 + r) * 1024 + k0 + scol];
            if (needLo)
                *(uint4*)&As[1][r][scol] =
                    *(const uint4*)&xl[(size_t)(m0 + r) * 1024 + k0 + scol];
            int o = n0 + r;
            uint4 b4 = make_uint4(0, 0, 0, 0), b4l = make_uint4(0, 0, 0, 0);
            if (o < 3088) {
                b4 = *(const uint4*)&wh[(size_t)o * 1024 + k0 + scol];
                if (needLo) b4l = *(const uint4*)&wl[(size_t)o * 1024 + k0 + scol];
            }
            *(uint4*)&Bs[0][r][scol] = b4;
            if (needLo) *(uint4*)&Bs[1][r][scol] = b4l;
        }
        __syncthreads();

        short8 ah[4], al[4], bh[4], bl[4];
#pragma unroll
        for (int i = 0; i < 4; ++i) {
            ah[i] = *(const short8*)&As[0][wm * 64 + i * 16 + lr][lq * 8];
            bh[i] = *(const short8*)&Bs[0][wn * 64 + i * 16 + lr][lq * 8];
        }
        if (needLo) {
#pragma unroll
            for (int i = 0; i < 4; ++i) {
                al[i] = *(const short8*)&As[1][wm * 64 + i * 16 + lr][lq * 8];
                bl[i] = *(const short8*)&Bs[1][wn * 64 + i * 16 + lr][lq * 8];
            }
        }
#pragma unroll
        for (int i = 0; i < 4; ++i)
#pragma unroll
            for (int j = 0; j < 4; ++j) {
                acc[i][j] = mfma_bf16(ah[i], bh[j], acc[i][j]);
                if (needLo) {
                    acc[i][j] = mfma_bf16(ah[i], bl[j], acc[i][j]);
                    acc[i][j] = mfma_bf16(al[i], bh[j], acc[i][j]);
                }
            }
    }

#pragma unroll
    for (int i = 0; i < 4; ++i) {
        int nrow0 = m0 + wm * 64 + i * 16 + lq * 4;
        int b = nrow0 >> 11;
        int tbase = nrow0 & 2047;
#pragma unroll
        for (int j = 0; j < 4; ++j) {
            int o = n0 + wn * 64 + j * 16 + lr;
            if (o < 1024) {
                int h = o >> 6, d = o & 63;
                size_t base = ((size_t)(b * 16 + h) * 2048 + tbase) * 64 + d;
#pragma unroll
                for (int r = 0; r < 4; ++r) {
                    float v = acc[i][j][r];
                    unsigned short hi_ = f2bf(v);
                    unsigned short lo_ = f2bf(v - bf2f(hi_));
                    Qh[base + (size_t)r * 64] = hi_;
                    Ql[base + (size_t)r * 64] = lo_;
                }
            } else if (o < 2048) {
                int oo = o - 1024;
                int h = oo >> 6, d = oo & 63;
                size_t base = ((size_t)(b * 16 + h) * 2048 + tbase) * 64 + d;
#pragma unroll
                for (int r = 0; r < 4; ++r) {
                    float v = acc[i][j][r];
                    unsigned short hi_ = f2bf(v);
                    unsigned short lo_ = f2bf(v - bf2f(hi_));
                    Kh[base + (size_t)r * 64] = hi_;
                    Kl[base + (size_t)r * 64] = lo_;
                }
            } else if (o < 3072) {
                int oo = o - 2048;
                int h = oo >> 6, d = oo & 63;
                size_t base = ((size_t)(b * 16 + h) * 64 + d) * 2048 + tbase;
                ushort4 pk;
                pk.x = f2bf(acc[i][j][0]);
                pk.y = f2bf(acc[i][j][1]);
                pk.z = f2bf(acc[i][j][2]);
                pk.w = f2bf(acc[i][j][3]);
                *(ushort4*)&Vtg[base] = pk;
            } else if (o < 3088) {
                int og = o - 3072;
#pragma unroll
                for (int r = 0; r < 4; ++r)
                    gbuf[(size_t)(nrow0 + r) * 16 + og] = acc[i][j][r];
            }
        }
    }
}

// ---------------------------------------------------------------------------
// Gate scan (unchanged): logG2[bh][t] = cumsum log_sigmoid * log2(e)
// ---------------------------------------------------------------------------
__global__ void gate_scan(const float* __restrict__ g, float* __restrict__ lg)
{
    const int bh = blockIdx.x;
    const int b = bh >> 4, h = bh & 15;
    const int tid = threadIdx.x;
    __shared__ float part[256];

    float vals[8];
    float run = 0.f;
#pragma unroll
    for (int j = 0; j < 8; ++j) {
        int t = tid * 8 + j;
        float x = g[(size_t)(b * 2048 + t) * 16 + h];
        float ls = fminf(x, 0.f) - log1pf(__expf(-fabsf(x)));
        run += ls * 1.4426950408889634f;
        vals[j] = run;
    }
    part[tid] = run;
    __syncthreads();
    for (int ofs = 1; ofs < 256; ofs <<= 1) {
        float add = (tid >= ofs) ? part[tid - ofs] : 0.f;
        __syncthreads();
        part[tid] += add;
        __syncthreads();
    }
    float excl = part[tid] - run;
#pragma unroll
    for (int j = 0; j < 8; ++j)
        lg[(size_t)bh * 2048 + tid * 8 + j] = excl + vals[j];
}

// ---------------------------------------------------------------------------
// Flash-style causal gated power attention — pipelined + balanced + linear-SM.
//  * launch_bounds(256,2): round-4's (256,4) forced a 128-reg clamp on the
//    unified VGPR/AGPR file -> massive scratch spills (WRITE_SIZE 339MB).
//  * gate loads moved out of LOADT (smaller live set across the pipeline)
// ---------------------------------------------------------------------------
__global__ __launch_bounds__(256, 2)
void attn_fwd(const unsigned short* __restrict__ Qh, const unsigned short* __restrict__ Ql,
              const unsigned short* __restrict__ Kh, const unsigned short* __restrict__ Kl,
              const unsigned short* __restrict__ Vtg, const float* __restrict__ lg,
              float* __restrict__ out)
{
    __shared__ __align__(16) unsigned short kh[64][64];
    __shared__ __align__(16) unsigned short kl[64][64];
    __shared__ __align__(16) unsigned short vs[64][64];   // [d][s]
    __shared__ __align__(16) unsigned short pl[4][16][64];

    const int bid = blockIdx.x;
    const int qi = (bid & 7) | ((bid >> 8) << 3);   // balance remap
    const int bh = (bid >> 3) & 31;
    const int tid = threadIdx.x;
    const int w = tid >> 6, l = tid & 63;
    const int lr = l & 15, lq = l >> 4;
    const int xk = lr & 7;
    const int q0 = qi * 64;
    const int myrow0 = q0 + w * 16;

    const size_t qoff = ((size_t)bh * 2048 + myrow0 + lr) * 64;
    short8 qh8[2], ql8[2];
    qh8[0] = *(const short8*)&Qh[qoff + lq * 8];
    qh8[1] = *(const short8*)&Qh[qoff + 32 + lq * 8];
    ql8[0] = *(const short8*)&Ql[qoff + lq * 8];
    ql8[1] = *(const short8*)&Ql[qoff + 32 + lq * 8];

    float gq2[4];
#pragma unroll
    for (int r = 0; r < 4; ++r)
        gq2[r] = lg[(size_t)bh * 2048 + myrow0 + lq * 4 + r] - 3.0f;  // + log2(1/8)

    float M_[4]  = {0.f, 0.f, 0.f, 0.f};
    float ls_[4] = {0.f, 0.f, 0.f, 0.f};
    f32x4 o4[4];
#pragma unroll
    for (int i = 0; i < 4; ++i) o4[i] = (f32x4){0.f, 0.f, 0.f, 0.f};

    // staging geometry: 256 thr x 16B covers 32 rows/pass, 2 passes per buffer
    const int srow = tid >> 3;          // 0..31
    const int schunk = tid & 7;         // 16B chunk
    const int swc = ((schunk ^ (srow & 7)) << 3);  // swizzled col (shorts)

    uint4 krh[2], krl[2], vr[2];

    auto LOADT = [&](int kv0) {
        size_t kb = ((size_t)bh * 2048 + kv0 + srow) * 64 + schunk * 8;
        krh[0] = *(const uint4*)&Kh[kb];
        krh[1] = *(const uint4*)&Kh[kb + 32 * 64];
        krl[0] = *(const uint4*)&Kl[kb];
        krl[1] = *(const uint4*)&Kl[kb + 32 * 64];
        size_t vb = ((size_t)bh * 64 + srow) * 2048 + kv0 + schunk * 8;
        vr[0] = *(const uint4*)&Vtg[vb];
        vr[1] = *(const uint4*)&Vtg[vb + 32 * 2048];
    };

    LOADT(0);

    for (int kv0 = 0; kv0 <= q0; kv0 += 64) {
        __syncthreads();   // all waves done reading LDS of previous tile
        *(uint4*)&kh[srow][swc]      = krh[0];
        *(uint4*)&kh[srow + 32][swc] = krh[1];
        *(uint4*)&kl[srow][swc]      = krl[0];
        *(uint4*)&kl[srow + 32][swc] = krl[1];
        *(uint4*)&vs[srow][swc]      = vr[0];
        *(uint4*)&vs[srow + 32][swc] = vr[1];
        __syncthreads();   // LDS writes visible

        if (kv0 + 64 <= q0) LOADT(kv0 + 64);   // overlap with compute below

        // gate values for this tile's 4 column slots (L2-hot, hidden by MFMAs)
        float gsl[4];
#pragma unroll
        for (int js = 0; js < 4; ++js)
            gsl[js] = lg[(size_t)bh * 2048 + kv0 + js * 16 + lr];

        // ---- S = Q K^T (split-bf16, 3 MFMA) ----
        f32x4 sa[4];
#pragma unroll
        for (int js = 0; js < 4; ++js) sa[js] = (f32x4){0.f, 0.f, 0.f, 0.f};
#pragma unroll
        for (int js = 0; js < 4; ++js)
#pragma unroll
            for (int ks = 0; ks < 2; ++ks) {
                short8 kb  = *(const short8*)&kh[js * 16 + lr][((ks * 4 + lq) ^ xk) << 3];
                short8 kbl = *(const short8*)&kl[js * 16 + lr][((ks * 4 + lq) ^ xk) << 3];
                sa[js] = mfma_bf16(qh8[ks], kb,  sa[js]);
                sa[js] = mfma_bf16(qh8[ks], kbl, sa[js]);
                sa[js] = mfma_bf16(ql8[ks], kb,  sa[js]);
            }

        // ---- linear-domain scores: w = (|S|+eps)^2 * 2^(gq-gs) ----
        const bool diag = (kv0 == q0);
#pragma unroll
        for (int js = 0; js < 4; ++js) {
            float ga = gsl[js];
#pragma unroll
            for (int r = 0; r < 4; ++r) {
                float a = fabsf(sa[js][r]) + 1e-7f;
                float ex = exp2f(gq2[r] - ga);
                float wv = a * a * ex;
                if (diag && (js * 16 + lr > w * 16 + lq * 4 + r)) wv = 0.f;
                sa[js][r] = wv;
            }
        }

        // ---- online max/rescale (linear) ----
        float f_[4], rMv[4];
#pragma unroll
        for (int r = 0; r < 4; ++r) {
            float a = fmaxf(fmaxf(sa[0][r], sa[1][r]), fmaxf(sa[2][r], sa[3][r]));
#pragma unroll
            for (int msk = 1; msk < 16; msk <<= 1)
                a = fmaxf(a, __shfl_xor(a, msk, 16));
            float Mn = fmaxf(M_[r], a);
            // guard: Mn in denormal range -> v_rcp_f32 flushes input -> inf -> 0*inf = NaN.
            bool pos = Mn > 1e-30f;
            float rM = pos ? __builtin_amdgcn_rcpf(Mn) : 0.f;
            f_[r]  = pos ? M_[r] * rM : 1.f;
            rMv[r] = rM;
            M_[r]  = Mn;
        }

        float rs_[4] = {0.f, 0.f, 0.f, 0.f};
#pragma unroll
        for (int js = 0; js < 4; ++js)
#pragma unroll
            for (int r = 0; r < 4; ++r) {
                float pv = sa[js][r] * rMv[r];
                sa[js][r] = pv;
                rs_[r] += pv;
            }
#pragma unroll
        for (int r = 0; r < 4; ++r) {
            float s = rs_[r];
#pragma unroll
            for (int msk = 1; msk < 16; msk <<= 1)
                s += __shfl_xor(s, msk, 16);
            ls_[r] = ls_[r] * f_[r] + s;
        }
#pragma unroll
        for (int ds_ = 0; ds_ < 4; ++ds_)
#pragma unroll
            for (int r = 0; r < 4; ++r)
                o4[ds_][r] *= f_[r];

        // ---- P -> LDS (swizzled transpose, wave-local) ----
#pragma unroll
        for (int js = 0; js < 4; ++js)
#pragma unroll
            for (int r = 0; r < 4; ++r) {
                int prow = lq * 4 + r;
                int cch = (js * 2 + (lr >> 3)) ^ (prow & 7);
                pl[w][prow][(cch << 3) | (lr & 7)] = f2bf(sa[js][r]);
            }
        __asm__ volatile("s_waitcnt lgkmcnt(0)" ::: "memory");
        __builtin_amdgcn_sched_barrier(0);

        short8 pa0 = *(const short8*)&pl[w][lr][((0 + lq) ^ xk) << 3];
        short8 pa1 = *(const short8*)&pl[w][lr][((4 + lq) ^ xk) << 3];
#pragma unroll
        for (int ds_ = 0; ds_ < 4; ++ds_) {
            short8 vb0 = *(const short8*)&vs[ds_ * 16 + lr][((0 + lq) ^ xk) << 3];
            short8 vb1 = *(const short8*)&vs[ds_ * 16 + lr][((4 + lq) ^ xk) << 3];
            o4[ds_] = mfma_bf16(pa0, vb0, o4[ds_]);
            o4[ds_] = mfma_bf16(pa1, vb1, o4[ds_]);
        }
    }

    const int b = bh >> 4, h = bh & 15;
#pragma unroll
    for (int ds_ = 0; ds_ < 4; ++ds_)
#pragma unroll
        for (int r = 0; r < 4; ++r) {
            int t = myrow0 + lq * 4 + r;
            out[(size_t)(b * 2048 + t) * 1024 + h * 64 + ds_ * 16 + lr] =
                o4[ds_][r] / ls_[r];
        }
}

// ---------------------------------------------------------------------------
extern "C" void kernel_launch(void* const* d_in, const int* in_sizes, int n_in,
                              void* d_out, int out_size, void* d_ws, size_t ws_size,
                              hipStream_t stream)
{
    const float* x = (const float*)d_in[0];   // [2][2048][1024]
    const float* W = (const float*)d_in[1];   // [3088][1024]
    float* out = (float*)d_out;               // [2][2048][1024]

    const size_t NX = 4194304;    // 2*2048*1024
    const size_t NW = 3162112;    // 3088*1024
    const size_t NQ = 4194304;    // 32*2048*64

    char* ws = (char*)d_ws;
    size_t off = 0;
    auto alloc = [&](size_t bytes) -> void* {
        void* p = ws + off;
        off += (bytes + 255) & ~(size_t)255;
        return p;
    };
    unsigned short* xh = (unsigned short*)alloc(NX * 2);
    unsigned short* xl = (unsigned short*)alloc(NX * 2);
    unsigned short* wh = (unsigned short*)alloc(NW * 2);
    unsigned short* wl = (unsigned short*)alloc(NW * 2);
    unsigned short* Qh = (unsigned short*)alloc(NQ * 2);
    unsigned short* Ql = (unsigned short*)alloc(NQ * 2);
    unsigned short* Kh = (unsigned short*)alloc(NQ * 2);
    unsigned short* Kl = (unsigned short*)alloc(NQ * 2);
    unsigned short* Vt = (unsigned short*)alloc(NQ * 2);
    float* g  = (float*)alloc(65536 * 4);
    float* lg = (float*)alloc(65536 * 4);
    if (off > ws_size) return;

    split_kernel<<<(int)(NX / 4 + 255) / 256, 256, 0, stream>>>(x, xh, xl, (int)(NX / 4));
    split_kernel<<<(int)(NW / 4 + 255) / 256, 256, 0, stream>>>(W, wh, wl, (int)(NW / 4));
    gemm_proj<<<800, 256, 0, stream>>>(xh, xl, wh, wl, Qh, Ql, Kh, Kl, Vt, g);
    gate_scan<<<32, 256, 0, stream>>>(g, lg);
    attn_fwd<<<1024, 256, 0, stream>>>(Qh, Ql, Kh, Kl, Vt, lg, out);
}

// Round 7
// 258.505 us; speedup vs baseline: 1.2894x; 1.2561x over previous
//
#include <hip/hip_runtime.h>
#include <math.h>

typedef __attribute__((ext_vector_type(4))) float f32x4;
typedef __attribute__((ext_vector_type(8))) short short8;

#define NEG_INF (-__builtin_inff())

__device__ __forceinline__ unsigned short f2bf(float f) {
    union { float f; unsigned u; } v; v.f = f;
    unsigned r = v.u + 0x7FFFu + ((v.u >> 16) & 1u);
    return (unsigned short)(r >> 16);
}
__device__ __forceinline__ float bf2f(unsigned short h) {
    union { unsigned u; float f; } v; v.u = ((unsigned)h) << 16;
    return v.f;
}

__device__ __forceinline__ f32x4 mfma_bf16(short8 a, short8 b, f32x4 c) {
    return __builtin_amdgcn_mfma_f32_16x16x32_bf16(a, b, c, 0, 0, 0);
}

// direct HBM->LDS DMA, 16B per lane, no VGPR round-trip
__device__ __forceinline__ void gload_lds16(const unsigned short* g, unsigned short* l) {
    __builtin_amdgcn_global_load_lds(
        (const __attribute__((address_space(1))) void*)g,
        (__attribute__((address_space(3))) void*)l, 16, 0, 0);
}

// ---------------------------------------------------------------------------
// Split fp32 -> (bf16 hi, bf16 lo) arrays, 4 elements per thread
// ---------------------------------------------------------------------------
__global__ void split_kernel(const float* __restrict__ in,
                             unsigned short* __restrict__ hi,
                             unsigned short* __restrict__ lo, int n4)
{
    int i = blockIdx.x * 256 + threadIdx.x;
    if (i >= n4) return;
    float4 v = ((const float4*)in)[i];
    ushort4 h, l;
    h.x = f2bf(v.x); l.x = f2bf(v.x - bf2f(h.x));
    h.y = f2bf(v.y); l.y = f2bf(v.y - bf2f(h.y));
    h.z = f2bf(v.z); l.z = f2bf(v.z - bf2f(h.z));
    h.w = f2bf(v.w); l.w = f2bf(v.w - bf2f(h.w));
    ((ushort4*)hi)[i] = h;
    ((ushort4*)lo)[i] = l;
}

// ---------------------------------------------------------------------------
// Projection GEMM (unchanged this round): qkvgr = x @ W^T
// ---------------------------------------------------------------------------
__global__ __launch_bounds__(256, 2)
void gemm_proj(const unsigned short* __restrict__ xh, const unsigned short* __restrict__ xl,
               const unsigned short* __restrict__ wh, const unsigned short* __restrict__ wl,
               unsigned short* __restrict__ Qh, unsigned short* __restrict__ Ql,
               unsigned short* __restrict__ Kh, unsigned short* __restrict__ Kl,
               unsigned short* __restrict__ Vtg, float* __restrict__ gbuf)
{
    __shared__ __align__(16) unsigned short As[2][128][40];
    __shared__ __align__(16) unsigned short Bs[2][128][40];
    const int mt = blockIdx.x & 31;
    const int nt = blockIdx.x >> 5;
    const int m0 = mt * 128, n0 = nt * 128;
    const int tid = threadIdx.x;
    const int w = tid >> 6, l = tid & 63;
    const int wm = w >> 1, wn = w & 1;
    const int lr = l & 15, lq = l >> 4;
    const bool needLo = (nt < 16) || (nt == 24);

    f32x4 acc[4][4];
#pragma unroll
    for (int i = 0; i < 4; ++i)
#pragma unroll
        for (int j = 0; j < 4; ++j) acc[i][j] = (f32x4){0.f, 0.f, 0.f, 0.f};

    const int srow = tid >> 2;
    const int scol = (tid & 3) * 8;

    for (int k0 = 0; k0 < 1024; k0 += 32) {
        __syncthreads();
#pragma unroll
        for (int p = 0; p < 2; ++p) {
            int r = srow + p * 64;
            *(uint4*)&As[0][r][scol] =
                *(const uint4*)&xh[(size_t)(m0 + r) * 1024 + k0 + scol];
            if (needLo)
                *(uint4*)&As[1][r][scol] =
                    *(const uint4*)&xl[(size_t)(m0 + r) * 1024 + k0 + scol];
            int o = n0 + r;
            uint4 b4 = make_uint4(0, 0, 0, 0), b4l = make_uint4(0, 0, 0, 0);
            if (o < 3088) {
                b4 = *(const uint4*)&wh[(size_t)o * 1024 + k0 + scol];
                if (needLo) b4l = *(const uint4*)&wl[(size_t)o * 1024 + k0 + scol];
            }
            *(uint4*)&Bs[0][r][scol] = b4;
            if (needLo) *(uint4*)&Bs[1][r][scol] = b4l;
        }
        __syncthreads();

        short8 ah[4], al[4], bh[4], bl[4];
#pragma unroll
        for (int i = 0; i < 4; ++i) {
            ah[i] = *(const short8*)&As[0][wm * 64 + i * 16 + lr][lq * 8];
            bh[i] = *(const short8*)&Bs[0][wn * 64 + i * 16 + lr][lq * 8];
        }
        if (needLo) {
#pragma unroll
            for (int i = 0; i < 4; ++i) {
                al[i] = *(const short8*)&As[1][wm * 64 + i * 16 + lr][lq * 8];
                bl[i] = *(const short8*)&Bs[1][wn * 64 + i * 16 + lr][lq * 8];
            }
        }
#pragma unroll
        for (int i = 0; i < 4; ++i)
#pragma unroll
            for (int j = 0; j < 4; ++j) {
                acc[i][j] = mfma_bf16(ah[i], bh[j], acc[i][j]);
                if (needLo) {
                    acc[i][j] = mfma_bf16(ah[i], bl[j], acc[i][j]);
                    acc[i][j] = mfma_bf16(al[i], bh[j], acc[i][j]);
                }
            }
    }

#pragma unroll
    for (int i = 0; i < 4; ++i) {
        int nrow0 = m0 + wm * 64 + i * 16 + lq * 4;
        int b = nrow0 >> 11;
        int tbase = nrow0 & 2047;
#pragma unroll
        for (int j = 0; j < 4; ++j) {
            int o = n0 + wn * 64 + j * 16 + lr;
            if (o < 1024) {
                int h = o >> 6, d = o & 63;
                size_t base = ((size_t)(b * 16 + h) * 2048 + tbase) * 64 + d;
#pragma unroll
                for (int r = 0; r < 4; ++r) {
                    float v = acc[i][j][r];
                    unsigned short hi_ = f2bf(v);
                    unsigned short lo_ = f2bf(v - bf2f(hi_));
                    Qh[base + (size_t)r * 64] = hi_;
                    Ql[base + (size_t)r * 64] = lo_;
                }
            } else if (o < 2048) {
                int oo = o - 1024;
                int h = oo >> 6, d = oo & 63;
                size_t base = ((size_t)(b * 16 + h) * 2048 + tbase) * 64 + d;
#pragma unroll
                for (int r = 0; r < 4; ++r) {
                    float v = acc[i][j][r];
                    unsigned short hi_ = f2bf(v);
                    unsigned short lo_ = f2bf(v - bf2f(hi_));
                    Kh[base + (size_t)r * 64] = hi_;
                    Kl[base + (size_t)r * 64] = lo_;
                }
            } else if (o < 3072) {
                int oo = o - 2048;
                int h = oo >> 6, d = oo & 63;
                size_t base = ((size_t)(b * 16 + h) * 64 + d) * 2048 + tbase;
                ushort4 pk;
                pk.x = f2bf(acc[i][j][0]);
                pk.y = f2bf(acc[i][j][1]);
                pk.z = f2bf(acc[i][j][2]);
                pk.w = f2bf(acc[i][j][3]);
                *(ushort4*)&Vtg[base] = pk;
            } else if (o < 3088) {
                int og = o - 3072;
#pragma unroll
                for (int r = 0; r < 4; ++r)
                    gbuf[(size_t)(nrow0 + r) * 16 + og] = acc[i][j][r];
            }
        }
    }
}

// ---------------------------------------------------------------------------
// Gate scan (unchanged): logG2[bh][t] = cumsum log_sigmoid * log2(e)
// ---------------------------------------------------------------------------
__global__ void gate_scan(const float* __restrict__ g, float* __restrict__ lg)
{
    const int bh = blockIdx.x;
    const int b = bh >> 4, h = bh & 15;
    const int tid = threadIdx.x;
    __shared__ float part[256];

    float vals[8];
    float run = 0.f;
#pragma unroll
    for (int j = 0; j < 8; ++j) {
        int t = tid * 8 + j;
        float x = g[(size_t)(b * 2048 + t) * 16 + h];
        float ls = fminf(x, 0.f) - log1pf(__expf(-fabsf(x)));
        run += ls * 1.4426950408889634f;
        vals[j] = run;
    }
    part[tid] = run;
    __syncthreads();
    for (int ofs = 1; ofs < 256; ofs <<= 1) {
        float add = (tid >= ofs) ? part[tid - ofs] : 0.f;
        __syncthreads();
        part[tid] += add;
        __syncthreads();
    }
    float excl = part[tid] - run;
#pragma unroll
    for (int j = 0; j < 8; ++j)
        lg[(size_t)bh * 2048 + tid * 8 + j] = excl + vals[j];
}

// ---------------------------------------------------------------------------
// Flash-style causal gated power attention.
//  * staging via global_load_lds (width 16): ZERO staging VGPRs, no ds_write.
//    Round 4/6's reg-staging pipeline forced scratch spills (VGPR clamp 64,
//    WRITE_SIZE 355MB) -> serialized VMEM latency, 195us.
//  * swizzle preserved per both-sides rule: linear LDS dest + inverse-swizzled
//    GLOBAL source chunk (c ^ (row&7)) + same XOR on read.
//  * single LDS buffer (32KB), serial stage; launch_bounds(256,3) -> no spill.
// ---------------------------------------------------------------------------
__global__ __launch_bounds__(256, 3)
void attn_fwd(const unsigned short* __restrict__ Qh, const unsigned short* __restrict__ Ql,
              const unsigned short* __restrict__ Kh, const unsigned short* __restrict__ Kl,
              const unsigned short* __restrict__ Vtg, const float* __restrict__ lg,
              float* __restrict__ out)
{
    __shared__ __align__(16) unsigned short kh[64][64];
    __shared__ __align__(16) unsigned short kl[64][64];
    __shared__ __align__(16) unsigned short vs[64][64];   // [d][s]
    __shared__ __align__(16) unsigned short pl[4][16][64];

    const int bid = blockIdx.x;
    const int qi = (bid & 7) | ((bid >> 8) << 3);   // balance remap
    const int bh = (bid >> 3) & 31;
    const int tid = threadIdx.x;
    const int w = tid >> 6, l = tid & 63;
    const int lr = l & 15, lq = l >> 4;
    const int xk = lr & 7;
    const int q0 = qi * 64;
    const int myrow0 = q0 + w * 16;

    const size_t qoff = ((size_t)bh * 2048 + myrow0 + lr) * 64;
    short8 qh8[2], ql8[2];
    qh8[0] = *(const short8*)&Qh[qoff + lq * 8];
    qh8[1] = *(const short8*)&Qh[qoff + 32 + lq * 8];
    ql8[0] = *(const short8*)&Ql[qoff + lq * 8];
    ql8[1] = *(const short8*)&Ql[qoff + 32 + lq * 8];

    float gq2[4];
#pragma unroll
    for (int r = 0; r < 4; ++r)
        gq2[r] = lg[(size_t)bh * 2048 + myrow0 + lq * 4 + r] - 3.0f;  // + log2(1/8)

    float M_[4]  = {0.f, 0.f, 0.f, 0.f};
    float ls_[4] = {0.f, 0.f, 0.f, 0.f};
    f32x4 o4[4];
#pragma unroll
    for (int i = 0; i < 4; ++i) o4[i] = (f32x4){0.f, 0.f, 0.f, 0.f};

    // staging geometry: thread -> (row = tid>>3, chunk = tid&7); lane offset in
    // LDS = l*16 from wave base (w*8+pass*32)*128 -> linear dest requirement OK.
    const int srow = tid >> 3;          // 0..31  (+32 on 2nd pass)
    const int schunk = tid & 7;         // 16B chunk index

    const unsigned short* Kh_b = Kh + (size_t)bh * 2048 * 64;
    const unsigned short* Kl_b = Kl + (size_t)bh * 2048 * 64;
    const unsigned short* Vt_b = Vtg + (size_t)bh * 64 * 2048;

    for (int kv0 = 0; kv0 <= q0; kv0 += 64) {
        __syncthreads();   // all waves done reading LDS of previous tile
#pragma unroll
        for (int p = 0; p < 2; ++p) {
            int r = srow + p * 32;
            int sc = (schunk ^ (r & 7)) * 8;     // inverse-swizzled source chunk
            gload_lds16(&Kh_b[(size_t)(kv0 + r) * 64 + sc], &kh[r][schunk * 8]);
            gload_lds16(&Kl_b[(size_t)(kv0 + r) * 64 + sc], &kl[r][schunk * 8]);
            gload_lds16(&Vt_b[(size_t)r * 2048 + kv0 + sc], &vs[r][schunk * 8]);
        }
        __asm__ volatile("s_waitcnt vmcnt(0)" ::: "memory");
        __syncthreads();   // staged data visible to all waves

        // gate values for this tile's 4 column slots (L2-hot)
        float gsl[4];
#pragma unroll
        for (int js = 0; js < 4; ++js)
            gsl[js] = lg[(size_t)bh * 2048 + kv0 + js * 16 + lr];

        // ---- S = Q K^T (split-bf16, 3 MFMA) ----
        f32x4 sa[4];
#pragma unroll
        for (int js = 0; js < 4; ++js) sa[js] = (f32x4){0.f, 0.f, 0.f, 0.f};
#pragma unroll
        for (int js = 0; js < 4; ++js)
#pragma unroll
            for (int ks = 0; ks < 2; ++ks) {
                short8 kb  = *(const short8*)&kh[js * 16 + lr][((ks * 4 + lq) ^ xk) << 3];
                short8 kbl = *(const short8*)&kl[js * 16 + lr][((ks * 4 + lq) ^ xk) << 3];
                sa[js] = mfma_bf16(qh8[ks], kb,  sa[js]);
                sa[js] = mfma_bf16(qh8[ks], kbl, sa[js]);
                sa[js] = mfma_bf16(ql8[ks], kb,  sa[js]);
            }

        // ---- linear-domain scores: w = (|S|+eps)^2 * 2^(gq-gs) ----
        const bool diag = (kv0 == q0);
#pragma unroll
        for (int js = 0; js < 4; ++js) {
            float ga = gsl[js];
#pragma unroll
            for (int r = 0; r < 4; ++r) {
                float a = fabsf(sa[js][r]) + 1e-7f;
                float ex = exp2f(gq2[r] - ga);
                float wv = a * a * ex;
                if (diag && (js * 16 + lr > w * 16 + lq * 4 + r)) wv = 0.f;
                sa[js][r] = wv;
            }
        }

        // ---- online max/rescale (linear) ----
        float f_[4], rMv[4];
#pragma unroll
        for (int r = 0; r < 4; ++r) {
            float a = fmaxf(fmaxf(sa[0][r], sa[1][r]), fmaxf(sa[2][r], sa[3][r]));
#pragma unroll
            for (int msk = 1; msk < 16; msk <<= 1)
                a = fmaxf(a, __shfl_xor(a, msk, 16));
            float Mn = fmaxf(M_[r], a);
            // guard: denormal Mn -> v_rcp flushes -> inf -> 0*inf = NaN
            bool pos = Mn > 1e-30f;
            float rM = pos ? __builtin_amdgcn_rcpf(Mn) : 0.f;
            f_[r]  = pos ? M_[r] * rM : 1.f;
            rMv[r] = rM;
            M_[r]  = Mn;
        }

        float rs_[4] = {0.f, 0.f, 0.f, 0.f};
#pragma unroll
        for (int js = 0; js < 4; ++js)
#pragma unroll
            for (int r = 0; r < 4; ++r) {
                float pv = sa[js][r] * rMv[r];
                sa[js][r] = pv;
                rs_[r] += pv;
            }
#pragma unroll
        for (int r = 0; r < 4; ++r) {
            float s = rs_[r];
#pragma unroll
            for (int msk = 1; msk < 16; msk <<= 1)
                s += __shfl_xor(s, msk, 16);
            ls_[r] = ls_[r] * f_[r] + s;
        }
#pragma unroll
        for (int ds_ = 0; ds_ < 4; ++ds_)
#pragma unroll
            for (int r = 0; r < 4; ++r)
                o4[ds_][r] *= f_[r];

        // ---- P -> LDS (swizzled transpose, wave-local) ----
#pragma unroll
        for (int js = 0; js < 4; ++js)
#pragma unroll
            for (int r = 0; r < 4; ++r) {
                int prow = lq * 4 + r;
                int cch = (js * 2 + (lr >> 3)) ^ (prow & 7);
                pl[w][prow][(cch << 3) | (lr & 7)] = f2bf(sa[js][r]);
            }
        __asm__ volatile("s_waitcnt lgkmcnt(0)" ::: "memory");
        __builtin_amdgcn_sched_barrier(0);

        short8 pa0 = *(const short8*)&pl[w][lr][((0 + lq) ^ xk) << 3];
        short8 pa1 = *(const short8*)&pl[w][lr][((4 + lq) ^ xk) << 3];
#pragma unroll
        for (int ds_ = 0; ds_ < 4; ++ds_) {
            short8 vb0 = *(const short8*)&vs[ds_ * 16 + lr][((0 + lq) ^ xk) << 3];
            short8 vb1 = *(const short8*)&vs[ds_ * 16 + lr][((4 + lq) ^ xk) << 3];
            o4[ds_] = mfma_bf16(pa0, vb0, o4[ds_]);
            o4[ds_] = mfma_bf16(pa1, vb1, o4[ds_]);
        }
    }

    const int b = bh >> 4, h = bh & 15;
#pragma unroll
    for (int ds_ = 0; ds_ < 4; ++ds_)
#pragma unroll
        for (int r = 0; r < 4; ++r) {
            int t = myrow0 + lq * 4 + r;
            out[(size_t)(b * 2048 + t) * 1024 + h * 64 + ds_ * 16 + lr] =
                o4[ds_][r] / ls_[r];
        }
}

// ---------------------------------------------------------------------------
extern "C" void kernel_launch(void* const* d_in, const int* in_sizes, int n_in,
                              void* d_out, int out_size, void* d_ws, size_t ws_size,
                              hipStream_t stream)
{
    const float* x = (const float*)d_in[0];   // [2][2048][1024]
    const float* W = (const float*)d_in[1];   // [3088][1024]
    float* out = (float*)d_out;               // [2][2048][1024]

    const size_t NX = 4194304;    // 2*2048*1024
    const size_t NW = 3162112;    // 3088*1024
    const size_t NQ = 4194304;    // 32*2048*64

    char* ws = (char*)d_ws;
    size_t off = 0;
    auto alloc = [&](size_t bytes) -> void* {
        void* p = ws + off;
        off += (bytes + 255) & ~(size_t)255;
        return p;
    };
    unsigned short* xh = (unsigned short*)alloc(NX * 2);
    unsigned short* xl = (unsigned short*)alloc(NX * 2);
    unsigned short* wh = (unsigned short*)alloc(NW * 2);
    unsigned short* wl = (unsigned short*)alloc(NW * 2);
    unsigned short* Qh = (unsigned short*)alloc(NQ * 2);
    unsigned short* Ql = (unsigned short*)alloc(NQ * 2);
    unsigned short* Kh = (unsigned short*)alloc(NQ * 2);
    unsigned short* Kl = (unsigned short*)alloc(NQ * 2);
    unsigned short* Vt = (unsigned short*)alloc(NQ * 2);
    float* g  = (float*)alloc(65536 * 4);
    float* lg = (float*)alloc(65536 * 4);
    if (off > ws_size) return;

    split_kernel<<<(int)(NX / 4 + 255) / 256, 256, 0, stream>>>(x, xh, xl, (int)(NX / 4));
    split_kernel<<<(int)(NW / 4 + 255) / 256, 256, 0, stream>>>(W, wh, wl, (int)(NW / 4));
    gemm_proj<<<800, 256, 0, stream>>>(xh, xl, wh, wl, Qh, Ql, Kh, Kl, Vt, g);
    gate_scan<<<32, 256, 0, stream>>>(g, lg);
    attn_fwd<<<1024, 256, 0, stream>>>(Qh, Ql, Kh, Kl, Vt, lg, out);
}

// Round 8
// 213.567 us; speedup vs baseline: 1.5607x; 1.2104x over previous
//
#include <hip/hip_runtime.h>
#include <math.h>

typedef __attribute__((ext_vector_type(4))) float f32x4;
typedef __attribute__((ext_vector_type(8))) short short8;

#define NEG_INF (-__builtin_inff())

__device__ __forceinline__ unsigned short f2bf(float f) {
    union { float f; unsigned u; } v; v.f = f;
    unsigned r = v.u + 0x7FFFu + ((v.u >> 16) & 1u);
    return (unsigned short)(r >> 16);
}
__device__ __forceinline__ float bf2f(unsigned short h) {
    union { unsigned u; float f; } v; v.u = ((unsigned)h) << 16;
    return v.f;
}

__device__ __forceinline__ f32x4 mfma_bf16(short8 a, short8 b, f32x4 c) {
    return __builtin_amdgcn_mfma_f32_16x16x32_bf16(a, b, c, 0, 0, 0);
}

// direct HBM->LDS DMA, 16B per lane, no VGPR round-trip
__device__ __forceinline__ void gload_lds16(const unsigned short* g, unsigned short* l) {
    __builtin_amdgcn_global_load_lds(
        (const __attribute__((address_space(1))) void*)g,
        (__attribute__((address_space(3))) void*)l, 16, 0, 0);
}

// ---------------------------------------------------------------------------
// Split fp32 -> (bf16 hi, bf16 lo) arrays, 4 elements per thread
// ---------------------------------------------------------------------------
__global__ void split_kernel(const float* __restrict__ in,
                             unsigned short* __restrict__ hi,
                             unsigned short* __restrict__ lo, int n4)
{
    int i = blockIdx.x * 256 + threadIdx.x;
    if (i >= n4) return;
    float4 v = ((const float4*)in)[i];
    ushort4 h, l;
    h.x = f2bf(v.x); l.x = f2bf(v.x - bf2f(h.x));
    h.y = f2bf(v.y); l.y = f2bf(v.y - bf2f(h.y));
    h.z = f2bf(v.z); l.z = f2bf(v.z - bf2f(h.z));
    h.w = f2bf(v.w); l.w = f2bf(v.w - bf2f(h.w));
    ((ushort4*)hi)[i] = h;
    ((ushort4*)lo)[i] = l;
}

// ---------------------------------------------------------------------------
// Projection GEMM: qkvgr = x @ W^T   (M=4096, N=3088->3200, K=1024)
//  * global_load_lds staging (attn-proven): no staging VGPRs, no ds_writes
//  * linear [128][32] LDS + XOR swizzle chunk^=(row>>1)&3 on BOTH source
//    address and fragment read -> 2-way bank aliasing only (free)
//  * split-bf16 (3 MFMA) for q,k,gate tiles; plain hi MFMA for v tiles
// ---------------------------------------------------------------------------
__global__ __launch_bounds__(256, 3)
void gemm_proj(const unsigned short* __restrict__ xh, const unsigned short* __restrict__ xl,
               const unsigned short* __restrict__ wh, const unsigned short* __restrict__ wl,
               unsigned short* __restrict__ Qh, unsigned short* __restrict__ Ql,
               unsigned short* __restrict__ Kh, unsigned short* __restrict__ Kl,
               unsigned short* __restrict__ Vtg, float* __restrict__ gbuf)
{
    __shared__ __align__(16) unsigned short Ah[128][32];
    __shared__ __align__(16) unsigned short Al[128][32];
    __shared__ __align__(16) unsigned short Bh[128][32];
    __shared__ __align__(16) unsigned short Bl[128][32];

    const int mt = blockIdx.x & 31;
    const int nt = blockIdx.x >> 5;        // 0..24
    const int m0 = mt * 128, n0 = nt * 128;
    const int tid = threadIdx.x;
    const int w = tid >> 6, l = tid & 63;
    const int wm = w >> 1, wn = w & 1;
    const int lr = l & 15, lq = l >> 4;
    const int xs = (lr >> 1) & 3;          // read-side swizzle selector
    const bool needLo = (nt < 16) || (nt == 24);

    f32x4 acc[4][4];
#pragma unroll
    for (int i = 0; i < 4; ++i)
#pragma unroll
        for (int j = 0; j < 4; ++j) acc[i][j] = (f32x4){0.f, 0.f, 0.f, 0.f};

    // staging geometry: row = tid>>2 (+64 on pass 2), physical 16B chunk = tid&3
    // LDS dest per wave is linear in lane (base + l*16) as gload_lds requires.
    const int srow = tid >> 2;     // 0..63
    const int sp = tid & 3;

    for (int k0 = 0; k0 < 1024; k0 += 32) {
        __syncthreads();
#pragma unroll
        for (int p = 0; p < 2; ++p) {
            int r = srow + p * 64;
            int sc = (sp ^ ((r >> 1) & 3)) * 8;   // inverse-swizzled source chunk
            int o = n0 + r;
            int oc = o < 3088 ? o : 3087;         // clamp OOB (values unused)
            gload_lds16(&xh[(size_t)(m0 + r) * 1024 + k0 + sc], &Ah[r][sp * 8]);
            gload_lds16(&wh[(size_t)oc * 1024 + k0 + sc],       &Bh[r][sp * 8]);
            if (needLo) {
                gload_lds16(&xl[(size_t)(m0 + r) * 1024 + k0 + sc], &Al[r][sp * 8]);
                gload_lds16(&wl[(size_t)oc * 1024 + k0 + sc],       &Bl[r][sp * 8]);
            }
        }
        __asm__ volatile("s_waitcnt vmcnt(0)" ::: "memory");
        __syncthreads();

        short8 ah[4], bh4[4], al4[4], bl4[4];
#pragma unroll
        for (int i = 0; i < 4; ++i) {
            ah[i]  = *(const short8*)&Ah[wm * 64 + i * 16 + lr][(lq ^ xs) * 8];
            bh4[i] = *(const short8*)&Bh[wn * 64 + i * 16 + lr][(lq ^ xs) * 8];
        }
        if (needLo) {
#pragma unroll
            for (int i = 0; i < 4; ++i) {
                al4[i] = *(const short8*)&Al[wm * 64 + i * 16 + lr][(lq ^ xs) * 8];
                bl4[i] = *(const short8*)&Bl[wn * 64 + i * 16 + lr][(lq ^ xs) * 8];
            }
        }
#pragma unroll
        for (int i = 0; i < 4; ++i)
#pragma unroll
            for (int j = 0; j < 4; ++j) {
                acc[i][j] = mfma_bf16(ah[i], bh4[j], acc[i][j]);
                if (needLo) {
                    acc[i][j] = mfma_bf16(ah[i], bl4[j], acc[i][j]);
                    acc[i][j] = mfma_bf16(al4[i], bh4[j], acc[i][j]);
                }
            }
    }

    // epilogue (unchanged)
#pragma unroll
    for (int i = 0; i < 4; ++i) {
        int nrow0 = m0 + wm * 64 + i * 16 + lq * 4;
        int b = nrow0 >> 11;
        int tbase = nrow0 & 2047;
#pragma unroll
        for (int j = 0; j < 4; ++j) {
            int o = n0 + wn * 64 + j * 16 + lr;
            if (o < 1024) {
                int h = o >> 6, d = o & 63;
                size_t base = ((size_t)(b * 16 + h) * 2048 + tbase) * 64 + d;
#pragma unroll
                for (int r = 0; r < 4; ++r) {
                    float v = acc[i][j][r];
                    unsigned short hi_ = f2bf(v);
                    unsigned short lo_ = f2bf(v - bf2f(hi_));
                    Qh[base + (size_t)r * 64] = hi_;
                    Ql[base + (size_t)r * 64] = lo_;
                }
            } else if (o < 2048) {
                int oo = o - 1024;
                int h = oo >> 6, d = oo & 63;
                size_t base = ((size_t)(b * 16 + h) * 2048 + tbase) * 64 + d;
#pragma unroll
                for (int r = 0; r < 4; ++r) {
                    float v = acc[i][j][r];
                    unsigned short hi_ = f2bf(v);
                    unsigned short lo_ = f2bf(v - bf2f(hi_));
                    Kh[base + (size_t)r * 64] = hi_;
                    Kl[base + (size_t)r * 64] = lo_;
                }
            } else if (o < 3072) {
                int oo = o - 2048;
                int h = oo >> 6, d = oo & 63;
                size_t base = ((size_t)(b * 16 + h) * 64 + d) * 2048 + tbase;
                ushort4 pk;
                pk.x = f2bf(acc[i][j][0]);
                pk.y = f2bf(acc[i][j][1]);
                pk.z = f2bf(acc[i][j][2]);
                pk.w = f2bf(acc[i][j][3]);
                *(ushort4*)&Vtg[base] = pk;
            } else if (o < 3088) {
                int og = o - 3072;
#pragma unroll
                for (int r = 0; r < 4; ++r)
                    gbuf[(size_t)(nrow0 + r) * 16 + og] = acc[i][j][r];
            }
        }
    }
}

// ---------------------------------------------------------------------------
// Gate scan (unchanged): logG2[bh][t] = cumsum log_sigmoid * log2(e)
// ---------------------------------------------------------------------------
__global__ void gate_scan(const float* __restrict__ g, float* __restrict__ lg)
{
    const int bh = blockIdx.x;
    const int b = bh >> 4, h = bh & 15;
    const int tid = threadIdx.x;
    __shared__ float part[256];

    float vals[8];
    float run = 0.f;
#pragma unroll
    for (int j = 0; j < 8; ++j) {
        int t = tid * 8 + j;
        float x = g[(size_t)(b * 2048 + t) * 16 + h];
        float ls = fminf(x, 0.f) - log1pf(__expf(-fabsf(x)));
        run += ls * 1.4426950408889634f;
        vals[j] = run;
    }
    part[tid] = run;
    __syncthreads();
    for (int ofs = 1; ofs < 256; ofs <<= 1) {
        float add = (tid >= ofs) ? part[tid - ofs] : 0.f;
        __syncthreads();
        part[tid] += add;
        __syncthreads();
    }
    float excl = part[tid] - run;
#pragma unroll
    for (int j = 0; j < 8; ++j)
        lg[(size_t)bh * 2048 + tid * 8 + j] = excl + vals[j];
}

// ---------------------------------------------------------------------------
// Flash-style causal gated power attention (unchanged from round 7).
// ---------------------------------------------------------------------------
__global__ __launch_bounds__(256, 3)
void attn_fwd(const unsigned short* __restrict__ Qh, const unsigned short* __restrict__ Ql,
              const unsigned short* __restrict__ Kh, const unsigned short* __restrict__ Kl,
              const unsigned short* __restrict__ Vtg, const float* __restrict__ lg,
              float* __restrict__ out)
{
    __shared__ __align__(16) unsigned short kh[64][64];
    __shared__ __align__(16) unsigned short kl[64][64];
    __shared__ __align__(16) unsigned short vs[64][64];   // [d][s]
    __shared__ __align__(16) unsigned short pl[4][16][64];

    const int bid = blockIdx.x;
    const int qi = (bid & 7) | ((bid >> 8) << 3);   // balance remap
    const int bh = (bid >> 3) & 31;
    const int tid = threadIdx.x;
    const int w = tid >> 6, l = tid & 63;
    const int lr = l & 15, lq = l >> 4;
    const int xk = lr & 7;
    const int q0 = qi * 64;
    const int myrow0 = q0 + w * 16;

    const size_t qoff = ((size_t)bh * 2048 + myrow0 + lr) * 64;
    short8 qh8[2], ql8[2];
    qh8[0] = *(const short8*)&Qh[qoff + lq * 8];
    qh8[1] = *(const short8*)&Qh[qoff + 32 + lq * 8];
    ql8[0] = *(const short8*)&Ql[qoff + lq * 8];
    ql8[1] = *(const short8*)&Ql[qoff + 32 + lq * 8];

    float gq2[4];
#pragma unroll
    for (int r = 0; r < 4; ++r)
        gq2[r] = lg[(size_t)bh * 2048 + myrow0 + lq * 4 + r] - 3.0f;  // + log2(1/8)

    float M_[4]  = {0.f, 0.f, 0.f, 0.f};
    float ls_[4] = {0.f, 0.f, 0.f, 0.f};
    f32x4 o4[4];
#pragma unroll
    for (int i = 0; i < 4; ++i) o4[i] = (f32x4){0.f, 0.f, 0.f, 0.f};

    const int srow = tid >> 3;          // 0..31  (+32 on 2nd pass)
    const int schunk = tid & 7;         // 16B chunk index

    const unsigned short* Kh_b = Kh + (size_t)bh * 2048 * 64;
    const unsigned short* Kl_b = Kl + (size_t)bh * 2048 * 64;
    const unsigned short* Vt_b = Vtg + (size_t)bh * 64 * 2048;

    for (int kv0 = 0; kv0 <= q0; kv0 += 64) {
        __syncthreads();   // all waves done reading LDS of previous tile
#pragma unroll
        for (int p = 0; p < 2; ++p) {
            int r = srow + p * 32;
            int sc = (schunk ^ (r & 7)) * 8;     // inverse-swizzled source chunk
            gload_lds16(&Kh_b[(size_t)(kv0 + r) * 64 + sc], &kh[r][schunk * 8]);
            gload_lds16(&Kl_b[(size_t)(kv0 + r) * 64 + sc], &kl[r][schunk * 8]);
            gload_lds16(&Vt_b[(size_t)r * 2048 + kv0 + sc], &vs[r][schunk * 8]);
        }
        __asm__ volatile("s_waitcnt vmcnt(0)" ::: "memory");
        __syncthreads();   // staged data visible to all waves

        float gsl[4];
#pragma unroll
        for (int js = 0; js < 4; ++js)
            gsl[js] = lg[(size_t)bh * 2048 + kv0 + js * 16 + lr];

        // ---- S = Q K^T (split-bf16, 3 MFMA) ----
        f32x4 sa[4];
#pragma unroll
        for (int js = 0; js < 4; ++js) sa[js] = (f32x4){0.f, 0.f, 0.f, 0.f};
#pragma unroll
        for (int js = 0; js < 4; ++js)
#pragma unroll
            for (int ks = 0; ks < 2; ++ks) {
                short8 kb  = *(const short8*)&kh[js * 16 + lr][((ks * 4 + lq) ^ xk) << 3];
                short8 kbl = *(const short8*)&kl[js * 16 + lr][((ks * 4 + lq) ^ xk) << 3];
                sa[js] = mfma_bf16(qh8[ks], kb,  sa[js]);
                sa[js] = mfma_bf16(qh8[ks], kbl, sa[js]);
                sa[js] = mfma_bf16(ql8[ks], kb,  sa[js]);
            }

        // ---- linear-domain scores: w = (|S|+eps)^2 * 2^(gq-gs) ----
        const bool diag = (kv0 == q0);
#pragma unroll
        for (int js = 0; js < 4; ++js) {
            float ga = gsl[js];
#pragma unroll
            for (int r = 0; r < 4; ++r) {
                float a = fabsf(sa[js][r]) + 1e-7f;
                float ex = exp2f(gq2[r] - ga);
                float wv = a * a * ex;
                if (diag && (js * 16 + lr > w * 16 + lq * 4 + r)) wv = 0.f;
                sa[js][r] = wv;
            }
        }

        // ---- online max/rescale (linear) ----
        float f_[4], rMv[4];
#pragma unroll
        for (int r = 0; r < 4; ++r) {
            float a = fmaxf(fmaxf(sa[0][r], sa[1][r]), fmaxf(sa[2][r], sa[3][r]));
#pragma unroll
            for (int msk = 1; msk < 16; msk <<= 1)
                a = fmaxf(a, __shfl_xor(a, msk, 16));
            float Mn = fmaxf(M_[r], a);
            // guard: denormal Mn -> v_rcp flushes -> inf -> 0*inf = NaN
            bool pos = Mn > 1e-30f;
            float rM = pos ? __builtin_amdgcn_rcpf(Mn) : 0.f;
            f_[r]  = pos ? M_[r] * rM : 1.f;
            rMv[r] = rM;
            M_[r]  = Mn;
        }

        float rs_[4] = {0.f, 0.f, 0.f, 0.f};
#pragma unroll
        for (int js = 0; js < 4; ++js)
#pragma unroll
            for (int r = 0; r < 4; ++r) {
                float pv = sa[js][r] * rMv[r];
                sa[js][r] = pv;
                rs_[r] += pv;
            }
#pragma unroll
        for (int r = 0; r < 4; ++r) {
            float s = rs_[r];
#pragma unroll
            for (int msk = 1; msk < 16; msk <<= 1)
                s += __shfl_xor(s, msk, 16);
            ls_[r] = ls_[r] * f_[r] + s;
        }
#pragma unroll
        for (int ds_ = 0; ds_ < 4; ++ds_)
#pragma unroll
            for (int r = 0; r < 4; ++r)
                o4[ds_][r] *= f_[r];

        // ---- P -> LDS (swizzled transpose, wave-local) ----
#pragma unroll
        for (int js = 0; js < 4; ++js)
#pragma unroll
            for (int r = 0; r < 4; ++r) {
                int prow = lq * 4 + r;
                int cch = (js * 2 + (lr >> 3)) ^ (prow & 7);
                pl[w][prow][(cch << 3) | (lr & 7)] = f2bf(sa[js][r]);
            }
        __asm__ volatile("s_waitcnt lgkmcnt(0)" ::: "memory");
        __builtin_amdgcn_sched_barrier(0);

        short8 pa0 = *(const short8*)&pl[w][lr][((0 + lq) ^ xk) << 3];
        short8 pa1 = *(const short8*)&pl[w][lr][((4 + lq) ^ xk) << 3];
#pragma unroll
        for (int ds_ = 0; ds_ < 4; ++ds_) {
            short8 vb0 = *(const short8*)&vs[ds_ * 16 + lr][((0 + lq) ^ xk) << 3];
            short8 vb1 = *(const short8*)&vs[ds_ * 16 + lr][((4 + lq) ^ xk) << 3];
            o4[ds_] = mfma_bf16(pa0, vb0, o4[ds_]);
            o4[ds_] = mfma_bf16(pa1, vb1, o4[ds_]);
        }
    }

    const int b = bh >> 4, h = bh & 15;
#pragma unroll
    for (int ds_ = 0; ds_ < 4; ++ds_)
#pragma unroll
        for (int r = 0; r < 4; ++r) {
            int t = myrow0 + lq * 4 + r;
            out[(size_t)(b * 2048 + t) * 1024 + h * 64 + ds_ * 16 + lr] =
                o4[ds_][r] / ls_[r];
        }
}

// ---------------------------------------------------------------------------
extern "C" void kernel_launch(void* const* d_in, const int* in_sizes, int n_in,
                              void* d_out, int out_size, void* d_ws, size_t ws_size,
                              hipStream_t stream)
{
    const float* x = (const float*)d_in[0];   // [2][2048][1024]
    const float* W = (const float*)d_in[1];   // [3088][1024]
    float* out = (float*)d_out;               // [2][2048][1024]

    const size_t NX = 4194304;    // 2*2048*1024
    const size_t NW = 3162112;    // 3088*1024
    const size_t NQ = 4194304;    // 32*2048*64

    char* ws = (char*)d_ws;
    size_t off = 0;
    auto alloc = [&](size_t bytes) -> void* {
        void* p = ws + off;
        off += (bytes + 255) & ~(size_t)255;
        return p;
    };
    unsigned short* xh = (unsigned short*)alloc(NX * 2);
    unsigned short* xl = (unsigned short*)alloc(NX * 2);
    unsigned short* wh = (unsigned short*)alloc(NW * 2);
    unsigned short* wl = (unsigned short*)alloc(NW * 2);
    unsigned short* Qh = (unsigned short*)alloc(NQ * 2);
    unsigned short* Ql = (unsigned short*)alloc(NQ * 2);
    unsigned short* Kh = (unsigned short*)alloc(NQ * 2);
    unsigned short* Kl = (unsigned short*)alloc(NQ * 2);
    unsigned short* Vt = (unsigned short*)alloc(NQ * 2);
    float* g  = (float*)alloc(65536 * 4);
    float* lg = (float*)alloc(65536 * 4);
    if (off > ws_size) return;

    split_kernel<<<(int)(NX / 4 + 255) / 256, 256, 0, stream>>>(x, xh, xl, (int)(NX / 4));
    split_kernel<<<(int)(NW / 4 + 255) / 256, 256, 0, stream>>>(W, wh, wl, (int)(NW / 4));
    gemm_proj<<<800, 256, 0, stream>>>(xh, xl, wh, wl, Qh, Ql, Kh, Kl, Vt, g);
    gate_scan<<<32, 256, 0, stream>>>(g, lg);
    attn_fwd<<<1024, 256, 0, stream>>>(Qh, Ql, Kh, Kl, Vt, lg, out);
}